// Round 12
// baseline (1098.647 us; speedup 1.0000x reference)
//
#include <hip/hip_runtime.h>

typedef _Float16 f16;
typedef __attribute__((ext_vector_type(8))) _Float16 f16x8;
typedef __attribute__((ext_vector_type(4))) float f32x4;
typedef __attribute__((ext_vector_type(16))) float f32x16;

#define SLICE_H 4326400   // 33800 padded positions * 128 ch (elements)

// ---------------- helpers ----------------

__device__ __forceinline__ void gld_lds16(void* lds, const void* g) {
  // async global->LDS, 16B per lane; LDS dest = wave-uniform base + lane*16
  __builtin_amdgcn_global_load_lds(
      (const __attribute__((address_space(1))) void*)g,
      (__attribute__((address_space(3))) void*)lds, 16, 0, 0);
}

__device__ __forceinline__ float sigf(float v) { return 1.0f / (1.0f + __expf(-v)); }
__device__ __forceinline__ float tanh_fast(float v) { return 2.0f / (1.0f + __expf(-2.0f * v)) - 1.0f; }

// ---------------- weight transforms ----------------

// output-conv weights: [O][I][3][3] -> [tap][O*I] f16 (no permutation)
__global__ __launch_bounds__(256) void kwt(const float* __restrict__ wsrc,
                                           f16* __restrict__ th, int R) {
  int idx = blockIdx.x * 256 + threadIdx.x;
  if (idx >= 9 * R) return;
  int tap = idx / R, r = idx - tap * R;     // r = cout*CIN + ci
  th[idx] = (f16)wsrc[(size_t)r * 9 + tap];
}

// gate weights, gate-interleaved at 32-granularity for 32x32 MFMA tiles:
//   original cout co = gate*128 + hch
//   new row N = (hch>>6)*256 + ((hch>>5)&1)*128 + gate*32 + (hch&31)
// block z = hch>>6, wave wn = (hch>>5)&1, MFMA n-tile nt == gate,
// lane&31 == hch&31 -> all 4 gates of one (px,hch) land in one thread's
// acc[mt][0..3] -> LSTM computed fully in registers.
__global__ __launch_bounds__(256) void kwtg(const float* __restrict__ wsrc,
                                            f16* __restrict__ th) {
  int idx = blockIdx.x * 256 + threadIdx.x;
  const int R = 512 * 192;
  if (idx >= 9 * R) return;
  int tap = idx / R, rr = idx - tap * R;
  int co = rr / 192, ci = rr - co * 192;
  int gate = co >> 7, hch = co & 127;
  int N = ((hch >> 6) << 8) + (((hch >> 5) & 1) << 7) + (gate << 5) + (hch & 31);
  th[(size_t)tap * R + (size_t)N * 192 + ci] = (f16)wsrc[(size_t)rr * 9 + tap];
}

// ---------------- x slice: NCHW fp32 -> padded NHWC f16 ----------------

__global__ __launch_bounds__(256) void kxform(const float* __restrict__ xt,
                                              f16* __restrict__ xp) {
  int pid = blockIdx.x * 256 + threadIdx.x;          // 2*128*128 pixels
  int b = pid >> 14, y = (pid >> 7) & 127, x = pid & 127;
  const float* src = xt + (size_t)b * 64 * 16384 + (size_t)y * 128 + x;
  size_t doff = ((size_t)((b * 130 + y + 1) * 130 + (x + 1))) * 64;
#pragma unroll
  for (int cc = 0; cc < 8; ++cc) {
    f16x8 vh;
#pragma unroll
    for (int j = 0; j < 8; ++j) vh[j] = (f16)src[(size_t)(cc * 8 + j) * 16384];
    *(f16x8*)(xp + doff + cc * 8) = vh;
  }
}

// ---------------- gate conv + fused LSTM (32x32x16 MFMA) ----------------
// implicit GEMM M=32768 N=512 K=1728; block: one y-row (128 px) x 256
// permuted couts; 4 waves (2M x 2N), wave tile 64x128 as 2 m-tiles x
// 4 n-tiles (n-tile == gate) of 32x32, acc = 2x4 f32x16.
// Per j (tap,cig): 16 mfma_32x32x16 (vs 32 of 16x16: half the instrs,
// ceiling 2495 vs 2075 TF) fed by the same 12 ds_read_b128.
// Counted-vmcnt ring-3 B prefetch, issue-early; A patch [3][132][32]
// halo-reused over 9 taps; XOR chunk-swizzle key=(row>>1)&3, k0-half
// flips slot via ^16.  Epilogue: LSTM in-register, c NCHW f32x4 I/O.

#define SMEM_G (25344 + 49152)

__global__ __launch_bounds__(256, 2) void kgates(
    const f16* __restrict__ xp, const f16* __restrict__ hp,
    const f16* __restrict__ wg, const float* __restrict__ bg,
    float* __restrict__ cbuf, f16* __restrict__ hslot) {
  extern __shared__ char smem[];
  f16* Ap = (f16*)smem;                    // [3][132][32]
  f16* Br = (f16*)(smem + 25344);          // ring [3][256][32]
  const int tid = threadIdx.x;
  const int lane = tid & 63;
  const int w = tid >> 6;
  const int l31 = lane & 31;
  const int h5 = lane >> 5;
  const int wm = w >> 1, wn = w & 1;
  const int y = blockIdx.x;
  const int b = blockIdx.y;
  const int z = blockIdx.z;
  const int n0 = z * 256;
  const int chunk = (lane & 3) ^ ((lane >> 3) & 3);
  const int slotB0 = (h5 ^ ((l31 >> 1) & 3)) << 3;   // per-thread const

  f32x16 acc[2][4] = {};

  // hoisted per-thread source base for B staging
  const f16* wgthr = wg + (size_t)(n0 + (lane >> 2)) * 192 + chunk * 8 + w * 3072;

  auto stageA = [&](int cig) {
    const f16* S; int CS, cigl;
    if (cig < 2) { S = xp; CS = 64;  cigl = cig; }
    else         { S = hp; CS = 128; cigl = cig - 2; }
    for (int i = w; i < 27; i += 4) {
      int dy = i / 9, sub = i - dy * 9;
      int xp0 = sub * 16;
      const f16* src = S +
          ((size_t)((b * 130 + y + dy) * 130 + xp0 + (lane >> 2))) * CS +
          cigl * 32 + chunk * 8;
      f16* dst = Ap + (dy * 132 + xp0) * 32;
      if (sub == 8) { if (lane < 16) gld_lds16(dst, src); }
      else gld_lds16(dst, src);
    }
  };
  auto stageB = [&](int j) {               // 4 loads/wave
    int cig = j / 9, tap = j - cig * 9;
    f16* dst = Br + (j % 3) * 8192 + w * 512;
    const f16* src = wgthr + (size_t)tap * (512 * 192) + cig * 32;
#pragma unroll
    for (int ii = 0; ii < 4; ++ii)
      gld_lds16(dst + ii * 2048, src + ii * 12288);
  };

  // prologue: A(0) + B(0) + B(1); keep B(1)'s 4 loads in flight
  stageA(0);
  stageB(0);
  stageB(1);
  asm volatile("s_waitcnt vmcnt(4)" ::: "memory");
  __builtin_amdgcn_s_barrier();

  for (int j = 0; j < 54; ++j) {
    const int cig = j / 9, tap = j - cig * 9;
    const int dy = tap / 3, dx = tap - dy * 3;

    if (j + 2 < 54) stageB(j + 2);         // issue-early: loads fly over MFMA

    const f16* Bc = Br + (j % 3) * 8192;
    const int rr = l31 + dx;
    const int slotA0 = (h5 ^ ((rr >> 1) & 3)) << 3;
    const f16* arow = Ap + dy * (132 * 32) + (wm * 64 + rr) * 32;
    const f16* brow = Bc + (wn * 128 + l31) * 32;
    f16x8 af[2][2], bfr[4][2];
#pragma unroll
    for (int mt = 0; mt < 2; ++mt) {
      af[mt][0] = *(const f16x8*)(arow + mt * 1024 + slotA0);
      af[mt][1] = *(const f16x8*)(arow + mt * 1024 + (slotA0 ^ 16));
    }
#pragma unroll
    for (int nt = 0; nt < 4; ++nt) {
      bfr[nt][0] = *(const f16x8*)(brow + nt * 1024 + slotB0);
      bfr[nt][1] = *(const f16x8*)(brow + nt * 1024 + (slotB0 ^ 16));
    }

    __builtin_amdgcn_s_setprio(1);
#pragma unroll
    for (int k = 0; k < 2; ++k)
#pragma unroll
      for (int mt = 0; mt < 2; ++mt)
#pragma unroll
        for (int nt = 0; nt < 4; ++nt)
          acc[mt][nt] = __builtin_amdgcn_mfma_f32_32x32x16_f16(
              af[mt][k], bfr[nt][k], acc[mt][nt], 0, 0, 0);
    __builtin_amdgcn_s_setprio(0);

    if (tap == 8) {
      __builtin_amdgcn_s_barrier();        // all waves done reading Ap
      if (cig < 5) stageA(cig + 1);
      asm volatile("s_waitcnt vmcnt(0)" ::: "memory");
      __builtin_amdgcn_s_barrier();
    } else {
      if (j + 2 < 54) asm volatile("s_waitcnt vmcnt(4)" ::: "memory");
      else            asm volatile("s_waitcnt vmcnt(0)" ::: "memory");
      __builtin_amdgcn_s_barrier();
    }
  }

  // fused LSTM epilogue.  C/D: col=lane&31, row=(reg&3)+8*(reg>>2)+4*h5.
  const int hch = z * 64 + wn * 32 + l31;
  const float bi  = bg[hch];
  const float bf2 = bg[128 + hch];
  const float bo2 = bg[256 + hch];
  const float bg2 = bg[384 + hch];
  float* crow = cbuf + ((size_t)(b * 128 + hch) * 128 + y) * 128;
  f16* hrow = hslot + ((size_t)((b * 130 + y + 1) * 130 + 1)) * 128 + hch;
#pragma unroll
  for (int mt = 0; mt < 2; ++mt) {
#pragma unroll
    for (int rq = 0; rq < 4; ++rq) {
      const int px0 = wm * 64 + mt * 32 + rq * 8 + h5 * 4;
      f32x4 co = *(const f32x4*)(crow + px0);
      f32x4 cn;
      f16 hv[4];
#pragma unroll
      for (int e = 0; e < 4; ++e) {
        const int reg = rq * 4 + e;
        float iv = sigf(acc[mt][0][reg] + bi);
        float fv = sigf(acc[mt][1][reg] + bf2);
        float ov = sigf(acc[mt][2][reg] + bo2);
        float gv = tanh_fast(acc[mt][3][reg] + bg2);
        float cv = fv * co[e] + iv * gv;
        cn[e] = cv;
        hv[e] = (f16)(ov * tanh_fast(cv));
      }
      *(f32x4*)(crow + px0) = cn;
#pragma unroll
      for (int e = 0; e < 4; ++e) hrow[(size_t)(px0 + e) * 128] = hv[e];
    }
  }
}

// ---------------- output conv, batched over 4 timesteps (32x32x16) ----------
// M=131072 N=64 K=1152; block: 128 px row x 64 couts; 4 waves M-split,
// wave tile 32x64 = 1 m-tile x 2 n-tiles, acc = 2 f32x16 (4 MFMA/j).

#define SMEM_O (25344 + 12288)

__global__ __launch_bounds__(256, 4) void koutconv(
    const f16* __restrict__ hr, int slot0, const f16* __restrict__ wo,
    const float* __restrict__ bo, float* __restrict__ outb) {
  extern __shared__ char smem[];
  f16* Ap = (f16*)smem;                    // [3][132][32]
  f16* Br = (f16*)(smem + 25344);          // ring [3][64][32]
  const int tid = threadIdx.x, lane = tid & 63, w = tid >> 6;
  const int l31 = lane & 31, h5 = lane >> 5;
  const int y = blockIdx.x;
  const int b = blockIdx.y;
  const int ts = blockIdx.z;
  const f16* hp = hr + (size_t)((slot0 + ts) % 5) * SLICE_H;
  float* outt = outb + (size_t)ts * 2 * 64 * 16384;
  const int chunk = (lane & 3) ^ ((lane >> 3) & 3);
  const int slotB0 = (h5 ^ ((l31 >> 1) & 3)) << 3;

  f32x16 acc[2] = {};

  const f16* wothr = wo + (size_t)(w * 16 + (lane >> 2)) * 128 + chunk * 8;

  auto stageA = [&](int cig) {
    for (int i = w; i < 27; i += 4) {
      int dy = i / 9, sub = i - dy * 9;
      int xp0 = sub * 16;
      const f16* src = hp +
          ((size_t)((b * 130 + y + dy) * 130 + xp0 + (lane >> 2))) * 128 +
          cig * 32 + chunk * 8;
      f16* dst = Ap + (dy * 132 + xp0) * 32;
      if (sub == 8) { if (lane < 16) gld_lds16(dst, src); }
      else gld_lds16(dst, src);
    }
  };
  auto stageB = [&](int j) {               // 1 load/wave
    int cig = j / 9, tap = j - cig * 9;
    gld_lds16(Br + (j % 3) * 2048 + w * 512,
              wothr + (size_t)tap * (64 * 128) + cig * 32);
  };

  stageA(0);
  stageB(0);
  stageB(1);
  asm volatile("s_waitcnt vmcnt(1)" ::: "memory");
  __builtin_amdgcn_s_barrier();

  for (int cig = 0; cig < 4; ++cig) {
    for (int tap = 0; tap < 9; ++tap) {
      const int j = cig * 9 + tap;
      const int dy = tap / 3, dx = tap - dy * 3;

      if (j + 2 < 36) stageB(j + 2);

      const f16* Bc = Br + (j % 3) * 2048;
      const int rr = l31 + dx;
      const int slotA0 = (h5 ^ ((rr >> 1) & 3)) << 3;
      const f16* arow = Ap + dy * (132 * 32) + (w * 32 + rr) * 32;
      const f16* brow = Bc + l31 * 32;
      f16x8 af[2], bfr[2][2];
      af[0] = *(const f16x8*)(arow + slotA0);
      af[1] = *(const f16x8*)(arow + (slotA0 ^ 16));
#pragma unroll
      for (int nt = 0; nt < 2; ++nt) {
        bfr[nt][0] = *(const f16x8*)(brow + nt * 1024 + slotB0);
        bfr[nt][1] = *(const f16x8*)(brow + nt * 1024 + (slotB0 ^ 16));
      }

      __builtin_amdgcn_s_setprio(1);
#pragma unroll
      for (int k = 0; k < 2; ++k)
#pragma unroll
        for (int nt = 0; nt < 2; ++nt)
          acc[nt] = __builtin_amdgcn_mfma_f32_32x32x16_f16(
              af[k], bfr[nt][k], acc[nt], 0, 0, 0);
      __builtin_amdgcn_s_setprio(0);

      if (tap == 8) {
        __builtin_amdgcn_s_barrier();
        if (cig < 3) stageA(cig + 1);
        asm volatile("s_waitcnt vmcnt(0)" ::: "memory");
        __builtin_amdgcn_s_barrier();
      } else {
        if (j + 2 < 36) asm volatile("s_waitcnt vmcnt(1)" ::: "memory");
        else            asm volatile("s_waitcnt vmcnt(0)" ::: "memory");
        __builtin_amdgcn_s_barrier();
      }
    }
  }

#pragma unroll
  for (int nt = 0; nt < 2; ++nt) {
    const int cout = nt * 32 + l31;
    const float bias = bo[cout];
    float* orow = outt + (((size_t)b * 64 + cout) * 128 + y) * 128;
#pragma unroll
    for (int rq = 0; rq < 4; ++rq) {
      const int px0 = w * 32 + rq * 8 + h5 * 4;
      f32x4 v;
#pragma unroll
      for (int e = 0; e < 4; ++e) v[e] = acc[nt][rq * 4 + e] + bias;
      *(f32x4*)(orow + px0) = v;
    }
  }
}

// ---------------- host ----------------

extern "C" void kernel_launch(void* const* d_in, const int* in_sizes, int n_in,
                              void* d_out, int out_size, void* d_ws, size_t ws_size,
                              hipStream_t stream) {
  const float* x  = (const float*)d_in[0];
  const float* Wg = (const float*)d_in[1];
  const float* bg = (const float*)d_in[2];
  const float* Wo = (const float*)d_in[3];
  const float* bo = (const float*)d_in[4];
  float* out = (float*)d_out;

  char* base = (char*)d_ws;
  size_t off = 0;
  auto carve = [&](size_t bytes) {
    char* p = base + off;
    off += (bytes + 1023) & ~(size_t)1023;
    return p;
  };
  const size_t PADPOS = (size_t)2 * 130 * 130;           // 33800 padded positions
  const size_t xpad_b  = PADPOS * 64 * 2 + 1024;          // f16
  const size_t hring_b = (size_t)5 * SLICE_H * 2 + 1024;  // 5 padded h slices, f16
  const size_t c_b = (size_t)2 * 128 * 128 * 128 * 4;     // fp32 cell state (NCHW)

  f16* xp    = (f16*)carve(xpad_b);
  f16* hr    = (f16*)carve(hring_b);
  float* cbuf = (float*)carve(c_b);
  f16* wg    = (f16*)carve((size_t)9 * 512 * 192 * 2);
  f16* wo    = (f16*)carve((size_t)9 * 64 * 128 * 2);

  // zero state + pad borders once (in-stream: graph-replay deterministic;
  // interiors are fully rewritten every use, borders stay zero)
  hipMemsetAsync(xp, 0, xpad_b, stream);
  hipMemsetAsync(hr, 0, hring_b, stream);
  hipMemsetAsync(cbuf, 0, c_b, stream);

  kwtg<<<(9 * 512 * 192 + 255) / 256, 256, 0, stream>>>(Wg, wg);
  kwt<<<(9 * 64 * 128 + 255) / 256, 256, 0, stream>>>(Wo, wo, 64 * 128);

  for (int t = 0; t < 12; ++t) {
    const float* xt = x + (size_t)t * 2 * 64 * 16384;
    kxform<<<128, 256, 0, stream>>>(xt, xp);
    kgates<<<dim3(128, 2, 2), 256, SMEM_G, stream>>>(
        xp, hr + (size_t)(t % 5) * SLICE_H, wg, bg, cbuf,
        hr + (size_t)((t + 1) % 5) * SLICE_H);
    if ((t & 3) == 3) {
      koutconv<<<dim3(128, 2, 4), 256, SMEM_O, stream>>>(
          hr, (t - 2) % 5, wo, bo, out + (size_t)(t - 3) * 2 * 64 * 16384);
    }
  }
}

// Round 13
// 1083.858 us; speedup vs baseline: 1.0136x; 1.0136x over previous
//
#include <hip/hip_runtime.h>

typedef _Float16 f16;
typedef __attribute__((ext_vector_type(8))) _Float16 f16x8;
typedef __attribute__((ext_vector_type(4))) float f32x4;
typedef __attribute__((ext_vector_type(16))) float f32x16;

#define SLICE_H 4326400   // 33800 padded positions * 128 ch (elements)

// ---------------- helpers ----------------

__device__ __forceinline__ void gld_lds16(void* lds, const void* g) {
  // async global->LDS, 16B per lane; LDS dest = wave-uniform base + lane*16
  __builtin_amdgcn_global_load_lds(
      (const __attribute__((address_space(1))) void*)g,
      (__attribute__((address_space(3))) void*)lds, 16, 0, 0);
}

__device__ __forceinline__ float sigf(float v) { return 1.0f / (1.0f + __expf(-v)); }
__device__ __forceinline__ float tanh_fast(float v) { return 2.0f / (1.0f + __expf(-2.0f * v)) - 1.0f; }

// ---------------- weight transforms ----------------

// output-conv weights: [O][I][3][3] -> [tap][O*I] f16 (no permutation)
__global__ __launch_bounds__(256) void kwt(const float* __restrict__ wsrc,
                                           f16* __restrict__ th, int R) {
  int idx = blockIdx.x * 256 + threadIdx.x;
  if (idx >= 9 * R) return;
  int tap = idx / R, r = idx - tap * R;     // r = cout*CIN + ci
  th[idx] = (f16)wsrc[(size_t)r * 9 + tap];
}

// gate weights, gate-interleaved at 32-granularity for 32x32 MFMA tiles:
//   original cout co = gate*128 + hch
//   new row N = (hch>>6)*256 + ((hch>>5)&1)*128 + gate*32 + (hch&31)
// block z = hch>>6, wave wn = (hch>>5)&1, MFMA n-tile nt == gate,
// lane&31 == hch&31 -> all 4 gates of one (px,hch) land in one thread's
// acc[mt][0..3] -> LSTM computed fully in registers.
__global__ __launch_bounds__(256) void kwtg(const float* __restrict__ wsrc,
                                            f16* __restrict__ th) {
  int idx = blockIdx.x * 256 + threadIdx.x;
  const int R = 512 * 192;
  if (idx >= 9 * R) return;
  int tap = idx / R, rr = idx - tap * R;
  int co = rr / 192, ci = rr - co * 192;
  int gate = co >> 7, hch = co & 127;
  int N = ((hch >> 6) << 8) + (((hch >> 5) & 1) << 7) + (gate << 5) + (hch & 31);
  th[(size_t)tap * R + (size_t)N * 192 + ci] = (f16)wsrc[(size_t)rr * 9 + tap];
}

// ---------------- x slice: NCHW fp32 -> padded NHWC f16 ----------------

__global__ __launch_bounds__(256) void kxform(const float* __restrict__ xt,
                                              f16* __restrict__ xp) {
  int pid = blockIdx.x * 256 + threadIdx.x;          // 2*128*128 pixels
  int b = pid >> 14, y = (pid >> 7) & 127, x = pid & 127;
  const float* src = xt + (size_t)b * 64 * 16384 + (size_t)y * 128 + x;
  size_t doff = ((size_t)((b * 130 + y + 1) * 130 + (x + 1))) * 64;
#pragma unroll
  for (int cc = 0; cc < 8; ++cc) {
    f16x8 vh;
#pragma unroll
    for (int j = 0; j < 8; ++j) vh[j] = (f16)src[(size_t)(cc * 8 + j) * 16384];
    *(f16x8*)(xp + doff + cc * 8) = vh;
  }
}

// ---------------- gate conv + fused LSTM (32x32x16 MFMA) ----------------
// implicit GEMM M=32768 N=512 K=1728; block: one y-row (128 px) x 256
// permuted couts; 4 waves (2M x 2N), wave tile 64x128 as 2 m-tiles x
// 4 n-tiles (n-tile == gate) of 32x32, acc = 2x4 f32x16.
// Swizzle key for 32-row fragments: key(row) = ((row>>1)&3) ^ ((row>>4)&1)
// -- the bit-4 term separates rows r / r+16, which share bank base
// (64B/row: 16 rows = 1024B = 0 mod 32 banks).  Every 16-lane phase then
// hits each bank pair exactly twice (2-way = free, m136).  Stage side
// pre-swizzles the global source (A: ^sub&1, B: ^w&1); read side XORs the
// same key.  Counted-vmcnt ring-3 B prefetch, issue-early; A patch
// [3][132][32] halo-reused over 9 taps.  Epilogue: LSTM in-register.

#define SMEM_G (25344 + 49152)

__global__ __launch_bounds__(256, 2) void kgates(
    const f16* __restrict__ xp, const f16* __restrict__ hp,
    const f16* __restrict__ wg, const float* __restrict__ bg,
    float* __restrict__ cbuf, f16* __restrict__ hslot) {
  extern __shared__ char smem[];
  f16* Ap = (f16*)smem;                    // [3][132][32]
  f16* Br = (f16*)(smem + 25344);          // ring [3][256][32]
  const int tid = threadIdx.x;
  const int lane = tid & 63;
  const int w = tid >> 6;
  const int l31 = lane & 31;
  const int h5 = lane >> 5;
  const int wm = w >> 1, wn = w & 1;
  const int y = blockIdx.x;
  const int b = blockIdx.y;
  const int z = blockIdx.z;
  const int n0 = z * 256;
  const int chunk = (lane & 3) ^ ((lane >> 3) & 3);
  // B read slot: key(n) = ((l31>>1)&3) ^ ((l31>>4)&1)  (per-thread const)
  const int slotB0 = (h5 ^ ((l31 >> 1) & 3) ^ ((l31 >> 4) & 1)) << 3;

  f32x16 acc[2][4] = {};

  // hoisted per-thread source base for B staging (chunk ^ (w&1): LDS row
  // bit4 of this wave's B rows is w&1)
  const f16* wgthr = wg + (size_t)(n0 + (lane >> 2)) * 192 +
                     (chunk ^ (w & 1)) * 8 + w * 3072;

  auto stageA = [&](int cig) {
    const f16* S; int CS, cigl;
    if (cig < 2) { S = xp; CS = 64;  cigl = cig; }
    else         { S = hp; CS = 128; cigl = cig - 2; }
    for (int i = w; i < 27; i += 4) {
      int dy = i / 9, sub = i - dy * 9;
      int xp0 = sub * 16;
      const f16* src = S +
          ((size_t)((b * 130 + y + dy) * 130 + xp0 + (lane >> 2))) * CS +
          cigl * 32 + (chunk ^ (sub & 1)) * 8;
      f16* dst = Ap + (dy * 132 + xp0) * 32;
      if (sub == 8) { if (lane < 16) gld_lds16(dst, src); }
      else gld_lds16(dst, src);
    }
  };
  auto stageB = [&](int j) {               // 4 loads/wave
    int cig = j / 9, tap = j - cig * 9;
    f16* dst = Br + (j % 3) * 8192 + w * 512;
    const f16* src = wgthr + (size_t)tap * (512 * 192) + cig * 32;
#pragma unroll
    for (int ii = 0; ii < 4; ++ii)
      gld_lds16(dst + ii * 2048, src + ii * 12288);
  };

  // prologue: A(0) + B(0) + B(1); keep B(1)'s 4 loads in flight
  stageA(0);
  stageB(0);
  stageB(1);
  asm volatile("s_waitcnt vmcnt(4)" ::: "memory");
  __builtin_amdgcn_s_barrier();

  for (int j = 0; j < 54; ++j) {
    const int cig = j / 9, tap = j - cig * 9;
    const int dy = tap / 3, dx = tap - dy * 3;

    if (j + 2 < 54) stageB(j + 2);         // issue-early: loads fly over MFMA

    const f16* Bc = Br + (j % 3) * 8192;
    const int rr = l31 + dx;
    const int slotA0 = (h5 ^ ((rr >> 1) & 3) ^ ((rr >> 4) & 1)) << 3;
    const f16* arow = Ap + dy * (132 * 32) + (wm * 64 + rr) * 32;
    const f16* brow = Bc + (wn * 128 + l31) * 32;
    f16x8 af[2][2], bfr[4][2];
#pragma unroll
    for (int mt = 0; mt < 2; ++mt) {
      af[mt][0] = *(const f16x8*)(arow + mt * 1024 + slotA0);
      af[mt][1] = *(const f16x8*)(arow + mt * 1024 + (slotA0 ^ 16));
    }
#pragma unroll
    for (int nt = 0; nt < 4; ++nt) {
      bfr[nt][0] = *(const f16x8*)(brow + nt * 1024 + slotB0);
      bfr[nt][1] = *(const f16x8*)(brow + nt * 1024 + (slotB0 ^ 16));
    }

    __builtin_amdgcn_s_setprio(1);
#pragma unroll
    for (int k = 0; k < 2; ++k)
#pragma unroll
      for (int mt = 0; mt < 2; ++mt)
#pragma unroll
        for (int nt = 0; nt < 4; ++nt)
          acc[mt][nt] = __builtin_amdgcn_mfma_f32_32x32x16_f16(
              af[mt][k], bfr[nt][k], acc[mt][nt], 0, 0, 0);
    __builtin_amdgcn_s_setprio(0);

    if (tap == 8) {
      __builtin_amdgcn_s_barrier();        // all waves done reading Ap
      if (cig < 5) stageA(cig + 1);
      asm volatile("s_waitcnt vmcnt(0)" ::: "memory");
      __builtin_amdgcn_s_barrier();
    } else {
      if (j + 2 < 54) asm volatile("s_waitcnt vmcnt(4)" ::: "memory");
      else            asm volatile("s_waitcnt vmcnt(0)" ::: "memory");
      __builtin_amdgcn_s_barrier();
    }
  }

  // fused LSTM epilogue.  C/D: col=lane&31, row=(reg&3)+8*(reg>>2)+4*h5.
  const int hch = z * 64 + wn * 32 + l31;
  const float bi  = bg[hch];
  const float bf2 = bg[128 + hch];
  const float bo2 = bg[256 + hch];
  const float bg2 = bg[384 + hch];
  float* crow = cbuf + ((size_t)(b * 128 + hch) * 128 + y) * 128;
  f16* hrow = hslot + ((size_t)((b * 130 + y + 1) * 130 + 1)) * 128 + hch;
#pragma unroll
  for (int mt = 0; mt < 2; ++mt) {
#pragma unroll
    for (int rq = 0; rq < 4; ++rq) {
      const int px0 = wm * 64 + mt * 32 + rq * 8 + h5 * 4;
      f32x4 co = *(const f32x4*)(crow + px0);
      f32x4 cn;
      f16 hv[4];
#pragma unroll
      for (int e = 0; e < 4; ++e) {
        const int reg = rq * 4 + e;
        float iv = sigf(acc[mt][0][reg] + bi);
        float fv = sigf(acc[mt][1][reg] + bf2);
        float ov = sigf(acc[mt][2][reg] + bo2);
        float gv = tanh_fast(acc[mt][3][reg] + bg2);
        float cv = fv * co[e] + iv * gv;
        cn[e] = cv;
        hv[e] = (f16)(ov * tanh_fast(cv));
      }
      *(f32x4*)(crow + px0) = cn;
#pragma unroll
      for (int e = 0; e < 4; ++e) hrow[(size_t)(px0 + e) * 128] = hv[e];
    }
  }
}

// ---------------- output conv, batched over 4 timesteps (32x32x16) ----------
// M=131072 N=64 K=1152; block: 128 px row x 64 couts; 4 waves M-split,
// wave tile 32x64 = 1 m-tile x 2 n-tiles, acc = 2 f32x16 (4 MFMA/j).
// Same bit-4-extended swizzle as kgates.

#define SMEM_O (25344 + 12288)

__global__ __launch_bounds__(256, 4) void koutconv(
    const f16* __restrict__ hr, int slot0, const f16* __restrict__ wo,
    const float* __restrict__ bo, float* __restrict__ outb) {
  extern __shared__ char smem[];
  f16* Ap = (f16*)smem;                    // [3][132][32]
  f16* Br = (f16*)(smem + 25344);          // ring [3][64][32]
  const int tid = threadIdx.x, lane = tid & 63, w = tid >> 6;
  const int l31 = lane & 31, h5 = lane >> 5;
  const int y = blockIdx.x;
  const int b = blockIdx.y;
  const int ts = blockIdx.z;
  const f16* hp = hr + (size_t)((slot0 + ts) % 5) * SLICE_H;
  float* outt = outb + (size_t)ts * 2 * 64 * 16384;
  const int chunk = (lane & 3) ^ ((lane >> 3) & 3);
  const int slotB0 = (h5 ^ ((l31 >> 1) & 3) ^ ((l31 >> 4) & 1)) << 3;

  f32x16 acc[2] = {};

  const f16* wothr = wo + (size_t)(w * 16 + (lane >> 2)) * 128 +
                     (chunk ^ (w & 1)) * 8;

  auto stageA = [&](int cig) {
    for (int i = w; i < 27; i += 4) {
      int dy = i / 9, sub = i - dy * 9;
      int xp0 = sub * 16;
      const f16* src = hp +
          ((size_t)((b * 130 + y + dy) * 130 + xp0 + (lane >> 2))) * 128 +
          cig * 32 + (chunk ^ (sub & 1)) * 8;
      f16* dst = Ap + (dy * 132 + xp0) * 32;
      if (sub == 8) { if (lane < 16) gld_lds16(dst, src); }
      else gld_lds16(dst, src);
    }
  };
  auto stageB = [&](int j) {               // 1 load/wave
    int cig = j / 9, tap = j - cig * 9;
    gld_lds16(Br + (j % 3) * 2048 + w * 512,
              wothr + (size_t)tap * (64 * 128) + cig * 32);
  };

  stageA(0);
  stageB(0);
  stageB(1);
  asm volatile("s_waitcnt vmcnt(1)" ::: "memory");
  __builtin_amdgcn_s_barrier();

  for (int cig = 0; cig < 4; ++cig) {
    for (int tap = 0; tap < 9; ++tap) {
      const int j = cig * 9 + tap;
      const int dy = tap / 3, dx = tap - dy * 3;

      if (j + 2 < 36) stageB(j + 2);

      const f16* Bc = Br + (j % 3) * 2048;
      const int rr = l31 + dx;
      const int slotA0 = (h5 ^ ((rr >> 1) & 3) ^ ((rr >> 4) & 1)) << 3;
      const f16* arow = Ap + dy * (132 * 32) + (w * 32 + rr) * 32;
      const f16* brow = Bc + l31 * 32;
      f16x8 af[2], bfr[2][2];
      af[0] = *(const f16x8*)(arow + slotA0);
      af[1] = *(const f16x8*)(arow + (slotA0 ^ 16));
#pragma unroll
      for (int nt = 0; nt < 2; ++nt) {
        bfr[nt][0] = *(const f16x8*)(brow + nt * 1024 + slotB0);
        bfr[nt][1] = *(const f16x8*)(brow + nt * 1024 + (slotB0 ^ 16));
      }

      __builtin_amdgcn_s_setprio(1);
#pragma unroll
      for (int k = 0; k < 2; ++k)
#pragma unroll
        for (int nt = 0; nt < 2; ++nt)
          acc[nt] = __builtin_amdgcn_mfma_f32_32x32x16_f16(
              af[k], bfr[nt][k], acc[nt], 0, 0, 0);
      __builtin_amdgcn_s_setprio(0);

      if (tap == 8) {
        __builtin_amdgcn_s_barrier();
        if (cig < 3) stageA(cig + 1);
        asm volatile("s_waitcnt vmcnt(0)" ::: "memory");
        __builtin_amdgcn_s_barrier();
      } else {
        if (j + 2 < 36) asm volatile("s_waitcnt vmcnt(1)" ::: "memory");
        else            asm volatile("s_waitcnt vmcnt(0)" ::: "memory");
        __builtin_amdgcn_s_barrier();
      }
    }
  }

#pragma unroll
  for (int nt = 0; nt < 2; ++nt) {
    const int cout = nt * 32 + l31;
    const float bias = bo[cout];
    float* orow = outt + (((size_t)b * 64 + cout) * 128 + y) * 128;
#pragma unroll
    for (int rq = 0; rq < 4; ++rq) {
      const int px0 = w * 32 + rq * 8 + h5 * 4;
      f32x4 v;
#pragma unroll
      for (int e = 0; e < 4; ++e) v[e] = acc[nt][rq * 4 + e] + bias;
      *(f32x4*)(orow + px0) = v;
    }
  }
}

// ---------------- host ----------------

extern "C" void kernel_launch(void* const* d_in, const int* in_sizes, int n_in,
                              void* d_out, int out_size, void* d_ws, size_t ws_size,
                              hipStream_t stream) {
  const float* x  = (const float*)d_in[0];
  const float* Wg = (const float*)d_in[1];
  const float* bg = (const float*)d_in[2];
  const float* Wo = (const float*)d_in[3];
  const float* bo = (const float*)d_in[4];
  float* out = (float*)d_out;

  char* base = (char*)d_ws;
  size_t off = 0;
  auto carve = [&](size_t bytes) {
    char* p = base + off;
    off += (bytes + 1023) & ~(size_t)1023;
    return p;
  };
  const size_t PADPOS = (size_t)2 * 130 * 130;           // 33800 padded positions
  const size_t xpad_b  = PADPOS * 64 * 2 + 1024;          // f16
  const size_t hring_b = (size_t)5 * SLICE_H * 2 + 1024;  // 5 padded h slices, f16
  const size_t c_b = (size_t)2 * 128 * 128 * 128 * 4;     // fp32 cell state (NCHW)

  f16* xp    = (f16*)carve(xpad_b);
  f16* hr    = (f16*)carve(hring_b);
  float* cbuf = (float*)carve(c_b);
  f16* wg    = (f16*)carve((size_t)9 * 512 * 192 * 2);
  f16* wo    = (f16*)carve((size_t)9 * 64 * 128 * 2);

  // zero state + pad borders once (in-stream: graph-replay deterministic;
  // interiors are fully rewritten every use, borders stay zero)
  hipMemsetAsync(xp, 0, xpad_b, stream);
  hipMemsetAsync(hr, 0, hring_b, stream);
  hipMemsetAsync(cbuf, 0, c_b, stream);

  kwtg<<<(9 * 512 * 192 + 255) / 256, 256, 0, stream>>>(Wg, wg);
  kwt<<<(9 * 64 * 128 + 255) / 256, 256, 0, stream>>>(Wo, wo, 64 * 128);

  for (int t = 0; t < 12; ++t) {
    const float* xt = x + (size_t)t * 2 * 64 * 16384;
    kxform<<<128, 256, 0, stream>>>(xt, xp);
    kgates<<<dim3(128, 2, 2), 256, SMEM_G, stream>>>(
        xp, hr + (size_t)(t % 5) * SLICE_H, wg, bg, cbuf,
        hr + (size_t)((t + 1) % 5) * SLICE_H);
    if ((t & 3) == 3) {
      koutconv<<<dim3(128, 2, 4), 256, SMEM_O, stream>>>(
          hr, (t - 2) % 5, wo, bo, out + (size_t)(t - 3) * 2 * 64 * 16384);
    }
  }
}

// Round 14
// 1080.390 us; speedup vs baseline: 1.0169x; 1.0032x over previous
//
#include <hip/hip_runtime.h>

typedef _Float16 f16;
typedef __attribute__((ext_vector_type(8))) _Float16 f16x8;
typedef __attribute__((ext_vector_type(4))) float f32x4;
typedef __attribute__((ext_vector_type(16))) float f32x16;

#define SLICE_H 4326400   // 33800 padded positions * 128 ch (elements)

// ---------------- helpers ----------------

__device__ __forceinline__ void gld_lds16(void* lds, const void* g) {
  // async global->LDS, 16B per lane; LDS dest = wave-uniform base + lane*16
  __builtin_amdgcn_global_load_lds(
      (const __attribute__((address_space(1))) void*)g,
      (__attribute__((address_space(3))) void*)lds, 16, 0, 0);
}

__device__ __forceinline__ float sigf(float v) { return 1.0f / (1.0f + __expf(-v)); }
__device__ __forceinline__ float tanh_fast(float v) { return 2.0f / (1.0f + __expf(-2.0f * v)) - 1.0f; }

// ---------------- weight transforms ----------------
// B is consumed from REGISTERS now: layout = panels [cig*9+tap][k][rows][16]
// so one wave-load per fragment is 1KB fully-coalesced
// (lane addr = row*32B + h5*16B).

// output-conv weights: [O][I][3][3] -> panels [cig*9+tap][k][64][16]
__global__ __launch_bounds__(256) void kwt(const float* __restrict__ wsrc,
                                           f16* __restrict__ th) {
  int idx = blockIdx.x * 256 + threadIdx.x;
  const int R = 64 * 128;
  if (idx >= 9 * R) return;
  int tap = idx / R, r = idx - tap * R;     // r = cout*128 + ci
  int co = r >> 7, ci = r & 127;
  int cig = ci >> 5, k = (ci >> 4) & 1, pos = ci & 15;
  th[((size_t)(cig * 9 + tap) * 2 + k) * 1024 + co * 16 + pos] =
      (f16)wsrc[(size_t)r * 9 + tap];
}

// gate weights: gate-interleaved cout permutation (32-granularity) +
// panel layout [cig*9+tap][k][512][16].
//   original cout co = gate*128 + hch
//   N = (hch>>6)*256 + ((hch>>5)&1)*128 + gate*32 + (hch&31)
// -> block z = hch>>6, wave wn = (hch>>5)&1, MFMA n-tile nt == gate:
// all 4 gates of one (px,hch) land in one thread's acc[mt][0..3].
__global__ __launch_bounds__(256) void kwtg(const float* __restrict__ wsrc,
                                            f16* __restrict__ th) {
  int idx = blockIdx.x * 256 + threadIdx.x;
  const int R = 512 * 192;
  if (idx >= 9 * R) return;
  int tap = idx / R, rr = idx - tap * R;
  int co = rr / 192, ci = rr - co * 192;
  int gate = co >> 7, hch = co & 127;
  int N = ((hch >> 6) << 8) + (((hch >> 5) & 1) << 7) + (gate << 5) + (hch & 31);
  int cig = ci >> 5, k = (ci >> 4) & 1, pos = ci & 15;
  th[((size_t)(cig * 9 + tap) * 2 + k) * 8192 + N * 16 + pos] =
      (f16)wsrc[(size_t)rr * 9 + tap];
}

// ---------------- x slice: NCHW fp32 -> padded NHWC f16 ----------------

__global__ __launch_bounds__(256) void kxform(const float* __restrict__ xt,
                                              f16* __restrict__ xp) {
  int pid = blockIdx.x * 256 + threadIdx.x;          // 2*128*128 pixels
  int b = pid >> 14, y = (pid >> 7) & 127, x = pid & 127;
  const float* src = xt + (size_t)b * 64 * 16384 + (size_t)y * 128 + x;
  size_t doff = ((size_t)((b * 130 + y + 1) * 130 + (x + 1))) * 64;
#pragma unroll
  for (int cc = 0; cc < 8; ++cc) {
    f16x8 vh;
#pragma unroll
    for (int j = 0; j < 8; ++j) vh[j] = (f16)src[(size_t)(cc * 8 + j) * 16384];
    *(f16x8*)(xp + doff + cc * 8) = vh;
  }
}

// ---------------- gate conv + fused LSTM (32x32x16, reg-B) ----------------
// implicit GEMM M=32768 N=512 K=1728; block: one y-row (128 px) x 256
// permuted couts; 4 waves (2M x 2N), wave tile 64x128 = 2 m-tiles x
// 4 n-tiles (nt == gate), acc = 2x4 f32x16.
// B goes L2 -> REGISTERS (coalesced 1KB loads, per-wave private):
// no B LDS, no per-tap barrier.  2-unrolled software pipeline b0/b1,
// prefetch 1 tap ahead (MFMA cluster covers L2 latency).  LDS = A patch
// only [3][132][32], halo-reused over 9 taps; barrier+drain at the 6 cig
// boundaries.  Epilogue: LSTM in-register, c NCHW f32x4 I/O.

#define SMEM_G 25344

__global__ __launch_bounds__(256, 2) void kgates(
    const f16* __restrict__ xp, const f16* __restrict__ hp,
    const f16* __restrict__ wg, const float* __restrict__ bg,
    float* __restrict__ cbuf, f16* __restrict__ hslot) {
  extern __shared__ char smem[];
  f16* Ap = (f16*)smem;                    // [3][132][32]
  const int tid = threadIdx.x;
  const int lane = tid & 63;
  const int w = tid >> 6;
  const int l31 = lane & 31;
  const int h5 = lane >> 5;
  const int wm = w >> 1, wn = w & 1;
  const int y = blockIdx.x;
  const int b = blockIdx.y;
  const int z = blockIdx.z;
  const int n0 = z * 256;
  const int chunk = (lane & 3) ^ ((lane >> 3) & 3);

  f32x16 acc[2][4] = {};

  // per-thread B source base (row = n0 + wn*128 + l31, half = h5)
  const f16* wgthr = wg + (size_t)(n0 + wn * 128 + l31) * 16 + h5 * 8;

  auto stageA = [&](int cig) {
    const f16* S; int CS, cigl;
    if (cig < 2) { S = xp; CS = 64;  cigl = cig; }
    else         { S = hp; CS = 128; cigl = cig - 2; }
    for (int i = w; i < 27; i += 4) {
      int dy = i / 9, sub = i - dy * 9;
      int xp0 = sub * 16;
      const f16* src = S +
          ((size_t)((b * 130 + y + dy) * 130 + xp0 + (lane >> 2))) * CS +
          cigl * 32 + (chunk ^ (sub & 1)) * 8;
      f16* dst = Ap + (dy * 132 + xp0) * 32;
      if (sub == 8) { if (lane < 16) gld_lds16(dst, src); }
      else gld_lds16(dst, src);
    }
  };

  struct BF { f16x8 v[8]; };
  auto loadB = [&](int j2, BF& f) {        // 8 coalesced 1KB loads
    const f16* p = wgthr + (size_t)j2 * 16384;
#pragma unroll
    for (int nt = 0; nt < 4; ++nt)
#pragma unroll
      for (int k = 0; k < 2; ++k)
        f.v[nt * 2 + k] = *(const f16x8*)(p + nt * 512 + k * 8192);
  };
  auto mfmaTap = [&](int j, const BF& bf) {
    const int cig = j / 9, tap = j - cig * 9;
    const int dy = tap / 3, dx = tap - dy * 3;
    const int rr = l31 + dx;
    const int slotA0 = (h5 ^ ((rr >> 1) & 3) ^ ((rr >> 4) & 1)) << 3;
    const f16* arow = Ap + dy * (132 * 32) + (wm * 64 + rr) * 32;
    f16x8 af[2][2];
#pragma unroll
    for (int mt = 0; mt < 2; ++mt) {
      af[mt][0] = *(const f16x8*)(arow + mt * 1024 + slotA0);
      af[mt][1] = *(const f16x8*)(arow + mt * 1024 + (slotA0 ^ 16));
    }
    __builtin_amdgcn_s_setprio(1);
#pragma unroll
    for (int k = 0; k < 2; ++k)
#pragma unroll
      for (int mt = 0; mt < 2; ++mt)
#pragma unroll
        for (int nt = 0; nt < 4; ++nt)
          acc[mt][nt] = __builtin_amdgcn_mfma_f32_32x32x16_f16(
              af[mt][k], bf.v[nt * 2 + k], acc[mt][nt], 0, 0, 0);
    __builtin_amdgcn_s_setprio(0);
  };
  auto cigEnd = [&](int cig) {
    __builtin_amdgcn_s_barrier();          // all waves done reading Ap
    if (cig < 5) stageA(cig + 1);
    asm volatile("s_waitcnt vmcnt(0)" ::: "memory");
    __builtin_amdgcn_s_barrier();
  };

  // prologue
  stageA(0);
  BF b0, b1;
  loadB(0, b0);
  asm volatile("s_waitcnt vmcnt(0)" ::: "memory");
  __builtin_amdgcn_s_barrier();

  for (int j = 0; j < 54; j += 2) {
    loadB(j + 1, b1);                      // prefetch flies over tap j
    mfmaTap(j, b0);
    if (j % 9 == 8) cigEnd(j / 9);         // j = 8, 26, 44
    if (j + 2 < 54) loadB(j + 2, b0);      // prefetch flies over tap j+1
    mfmaTap(j + 1, b1);
    if ((j + 1) % 9 == 8) cigEnd((j + 1) / 9);  // j+1 = 17, 35, 53
  }

  // fused LSTM epilogue.  C/D: col=lane&31, row=(reg&3)+8*(reg>>2)+4*h5.
  const int hch = z * 64 + wn * 32 + l31;
  const float bi  = bg[hch];
  const float bf2 = bg[128 + hch];
  const float bo2 = bg[256 + hch];
  const float bg2 = bg[384 + hch];
  float* crow = cbuf + ((size_t)(b * 128 + hch) * 128 + y) * 128;
  f16* hrow = hslot + ((size_t)((b * 130 + y + 1) * 130 + 1)) * 128 + hch;
#pragma unroll
  for (int mt = 0; mt < 2; ++mt) {
#pragma unroll
    for (int rq = 0; rq < 4; ++rq) {
      const int px0 = wm * 64 + mt * 32 + rq * 8 + h5 * 4;
      f32x4 co = *(const f32x4*)(crow + px0);
      f32x4 cn;
      f16 hv[4];
#pragma unroll
      for (int e = 0; e < 4; ++e) {
        const int reg = rq * 4 + e;
        float iv = sigf(acc[mt][0][reg] + bi);
        float fv = sigf(acc[mt][1][reg] + bf2);
        float ov = sigf(acc[mt][2][reg] + bo2);
        float gv = tanh_fast(acc[mt][3][reg] + bg2);
        float cv = fv * co[e] + iv * gv;
        cn[e] = cv;
        hv[e] = (f16)(ov * tanh_fast(cv));
      }
      *(f32x4*)(crow + px0) = cn;
#pragma unroll
      for (int e = 0; e < 4; ++e) hrow[(size_t)(px0 + e) * 128] = hv[e];
    }
  }
}

// ---------------- output conv, batched over 4 timesteps (32x32x16, reg-B) ----
// M=131072 N=64 K=1152; block: 128 px row x 64 couts; 4 waves M-split,
// wave tile 32x64 = 1 m-tile x 2 n-tiles, acc = 2 f32x16.
// Same reg-B pipeline; barriers only at the 4 cig boundaries.

#define SMEM_O 25344

__global__ __launch_bounds__(256, 4) void koutconv(
    const f16* __restrict__ hr, int slot0, const f16* __restrict__ wo,
    const float* __restrict__ bo, float* __restrict__ outb) {
  extern __shared__ char smem[];
  f16* Ap = (f16*)smem;                    // [3][132][32]
  const int tid = threadIdx.x, lane = tid & 63, w = tid >> 6;
  const int l31 = lane & 31, h5 = lane >> 5;
  const int y = blockIdx.x;
  const int b = blockIdx.y;
  const int ts = blockIdx.z;
  const f16* hp = hr + (size_t)((slot0 + ts) % 5) * SLICE_H;
  float* outt = outb + (size_t)ts * 2 * 64 * 16384;
  const int chunk = (lane & 3) ^ ((lane >> 3) & 3);

  f32x16 acc[2] = {};

  const f16* wothr = wo + (size_t)l31 * 16 + h5 * 8;

  auto stageA = [&](int cig) {
    for (int i = w; i < 27; i += 4) {
      int dy = i / 9, sub = i - dy * 9;
      int xp0 = sub * 16;
      const f16* src = hp +
          ((size_t)((b * 130 + y + dy) * 130 + xp0 + (lane >> 2))) * 128 +
          cig * 32 + (chunk ^ (sub & 1)) * 8;
      f16* dst = Ap + (dy * 132 + xp0) * 32;
      if (sub == 8) { if (lane < 16) gld_lds16(dst, src); }
      else gld_lds16(dst, src);
    }
  };

  struct BF { f16x8 v[4]; };
  auto loadB = [&](int j2, BF& f) {
    const f16* p = wothr + (size_t)j2 * 2048;
#pragma unroll
    for (int nt = 0; nt < 2; ++nt)
#pragma unroll
      for (int k = 0; k < 2; ++k)
        f.v[nt * 2 + k] = *(const f16x8*)(p + nt * 512 + k * 1024);
  };
  auto mfmaTap = [&](int j, const BF& bf) {
    const int cig = j / 9, tap = j - cig * 9;
    const int dy = tap / 3, dx = tap - dy * 3;
    const int rr = l31 + dx;
    const int slotA0 = (h5 ^ ((rr >> 1) & 3) ^ ((rr >> 4) & 1)) << 3;
    const f16* arow = Ap + dy * (132 * 32) + (w * 32 + rr) * 32;
    f16x8 af[2];
    af[0] = *(const f16x8*)(arow + slotA0);
    af[1] = *(const f16x8*)(arow + (slotA0 ^ 16));
    __builtin_amdgcn_s_setprio(1);
#pragma unroll
    for (int k = 0; k < 2; ++k)
#pragma unroll
      for (int nt = 0; nt < 2; ++nt)
        acc[nt] = __builtin_amdgcn_mfma_f32_32x32x16_f16(
            af[k], bf.v[nt * 2 + k], acc[nt], 0, 0, 0);
    __builtin_amdgcn_s_setprio(0);
  };
  auto cigEnd = [&](int cig) {
    __builtin_amdgcn_s_barrier();
    if (cig < 3) stageA(cig + 1);
    asm volatile("s_waitcnt vmcnt(0)" ::: "memory");
    __builtin_amdgcn_s_barrier();
  };

  stageA(0);
  BF b0, b1;
  loadB(0, b0);
  asm volatile("s_waitcnt vmcnt(0)" ::: "memory");
  __builtin_amdgcn_s_barrier();

  for (int j = 0; j < 36; j += 2) {
    loadB(j + 1, b1);
    mfmaTap(j, b0);
    if (j % 9 == 8) cigEnd(j / 9);         // j = 8, 26
    if (j + 2 < 36) loadB(j + 2, b0);
    mfmaTap(j + 1, b1);
    if ((j + 1) % 9 == 8) cigEnd((j + 1) / 9);  // j+1 = 17, 35
  }

#pragma unroll
  for (int nt = 0; nt < 2; ++nt) {
    const int cout = nt * 32 + l31;
    const float bias = bo[cout];
    float* orow = outt + (((size_t)b * 64 + cout) * 128 + y) * 128;
#pragma unroll
    for (int rq = 0; rq < 4; ++rq) {
      const int px0 = w * 32 + rq * 8 + h5 * 4;
      f32x4 v;
#pragma unroll
      for (int e = 0; e < 4; ++e) v[e] = acc[nt][rq * 4 + e] + bias;
      *(f32x4*)(orow + px0) = v;
    }
  }
}

// ---------------- host ----------------

extern "C" void kernel_launch(void* const* d_in, const int* in_sizes, int n_in,
                              void* d_out, int out_size, void* d_ws, size_t ws_size,
                              hipStream_t stream) {
  const float* x  = (const float*)d_in[0];
  const float* Wg = (const float*)d_in[1];
  const float* bg = (const float*)d_in[2];
  const float* Wo = (const float*)d_in[3];
  const float* bo = (const float*)d_in[4];
  float* out = (float*)d_out;

  char* base = (char*)d_ws;
  size_t off = 0;
  auto carve = [&](size_t bytes) {
    char* p = base + off;
    off += (bytes + 1023) & ~(size_t)1023;
    return p;
  };
  const size_t PADPOS = (size_t)2 * 130 * 130;           // 33800 padded positions
  const size_t xpad_b  = PADPOS * 64 * 2 + 1024;          // f16
  const size_t hring_b = (size_t)5 * SLICE_H * 2 + 1024;  // 5 padded h slices, f16
  const size_t c_b = (size_t)2 * 128 * 128 * 128 * 4;     // fp32 cell state (NCHW)

  f16* xp    = (f16*)carve(xpad_b);
  f16* hr    = (f16*)carve(hring_b);
  float* cbuf = (float*)carve(c_b);
  f16* wg    = (f16*)carve((size_t)54 * 2 * 512 * 16 * 2);  // panels
  f16* wo    = (f16*)carve((size_t)36 * 2 * 64 * 16 * 2);   // panels

  // zero state + pad borders once (in-stream: graph-replay deterministic;
  // interiors are fully rewritten every use, borders stay zero)
  hipMemsetAsync(xp, 0, xpad_b, stream);
  hipMemsetAsync(hr, 0, hring_b, stream);
  hipMemsetAsync(cbuf, 0, c_b, stream);

  kwtg<<<(9 * 512 * 192 + 255) / 256, 256, 0, stream>>>(Wg, wg);
  kwt<<<(9 * 64 * 128 + 255) / 256, 256, 0, stream>>>(Wo, wo);

  for (int t = 0; t < 12; ++t) {
    const float* xt = x + (size_t)t * 2 * 64 * 16384;
    kxform<<<128, 256, 0, stream>>>(xt, xp);
    kgates<<<dim3(128, 2, 2), 256, SMEM_G, stream>>>(
        xp, hr + (size_t)(t % 5) * SLICE_H, wg, bg, cbuf,
        hr + (size_t)((t + 1) % 5) * SLICE_H);
    if ((t & 3) == 3) {
      koutconv<<<dim3(128, 2, 4), 256, SMEM_O, stream>>>(
          hr, (t - 2) % 5, wo, bo, out + (size_t)(t - 3) * 2 * 64 * 16384);
    }
  }
}

// Round 15
// 977.024 us; speedup vs baseline: 1.1245x; 1.1058x over previous
//
#include <hip/hip_runtime.h>

typedef _Float16 f16;
typedef __attribute__((ext_vector_type(8))) _Float16 f16x8;
typedef __attribute__((ext_vector_type(4))) float f32x4;

#define SLICE_H 4326400   // 33800 padded positions * 128 ch (elements)

// ---------------- helpers ----------------

__device__ __forceinline__ void gld_lds16(void* lds, const void* g) {
  // async global->LDS, 16B per lane; LDS dest = wave-uniform base + lane*16
  __builtin_amdgcn_global_load_lds(
      (const __attribute__((address_space(1))) void*)g,
      (__attribute__((address_space(3))) void*)lds, 16, 0, 0);
}

__device__ __forceinline__ float sigf(float v) { return 1.0f / (1.0f + __expf(-v)); }
__device__ __forceinline__ float tanh_fast(float v) { return 2.0f / (1.0f + __expf(-2.0f * v)) - 1.0f; }

// ---------------- weight transforms ----------------

// output-conv weights: [O][I][3][3] -> [tap][O*I] f16 (no permutation)
__global__ __launch_bounds__(256) void kwt(const float* __restrict__ wsrc,
                                           f16* __restrict__ th, int R) {
  int idx = blockIdx.x * 256 + threadIdx.x;
  if (idx >= 9 * R) return;
  int tap = idx / R, r = idx - tap * R;     // r = cout*CIN + ci
  th[idx] = (f16)wsrc[(size_t)r * 9 + tap];
}

// gate weights with gate-interleaved cout permutation:
//   original cout co = gate*128 + hch  (gate: i,f,o,g)
//   new row N = (hch>>6)*256 + ((hch&63)>>4)*64 + gate*16 + (hch&15)
// so that: block z = hch>>6, wave w = (hch&63)>>4, MFMA frag nf == gate,
// lane&15 == hch low bits -> the 4 gates of one (px,lch) land in one
// thread's acc[mf][0..3] -> LSTM computed fully in registers.
__global__ __launch_bounds__(256) void kwtg(const float* __restrict__ wsrc,
                                            f16* __restrict__ th) {
  int idx = blockIdx.x * 256 + threadIdx.x;
  const int R = 512 * 192;
  if (idx >= 9 * R) return;
  int tap = idx / R, rr = idx - tap * R;
  int co = rr / 192, ci = rr - co * 192;
  int gate = co >> 7, hch = co & 127;
  int N = ((hch >> 6) << 8) + (((hch & 63) >> 4) << 6) + (gate << 4) + (hch & 15);
  th[(size_t)tap * R + (size_t)N * 192 + ci] = (f16)wsrc[(size_t)rr * 9 + tap];
}

// ---------------- x slice: NCHW fp32 -> padded NHWC f16 ----------------

__global__ __launch_bounds__(256) void kxform(const float* __restrict__ xt,
                                              f16* __restrict__ xp) {
  int pid = blockIdx.x * 256 + threadIdx.x;          // 2*128*128 pixels
  int b = pid >> 14, y = (pid >> 7) & 127, x = pid & 127;
  const float* src = xt + (size_t)b * 64 * 16384 + (size_t)y * 128 + x;
  size_t doff = ((size_t)((b * 130 + y + 1) * 130 + (x + 1))) * 64;
#pragma unroll
  for (int cc = 0; cc < 8; ++cc) {
    f16x8 vh;
#pragma unroll
    for (int j = 0; j < 8; ++j) vh[j] = (f16)src[(size_t)(cc * 8 + j) * 16384];
    *(f16x8*)(xp + doff + cc * 8) = vh;
  }
}

// ---------------- gate conv + fused LSTM (barrier-free taps) ----------------
// implicit GEMM M=32768 N=512 K=1728; block: one y-row (128 px) x 256
// permuted couts; 4 waves (N-split), wave tile 128x64 (acc[8][4]).
// KEY CHANGE vs R11: each wave stages ITS OWN 64 B-rows into a per-wave
// PRIVATE LDS ring [3][64][32] -> no cross-wave B dependency -> the 54
// per-tap barrier pairs are DELETED.  Sync is per-wave s_waitcnt vmcnt:
// steady state vmcnt(8) (own B(j+1),B(j+2) in flight), tail 4/0.  Same
// staging bytes, same LDS total (74.5KB -> 2 blocks/CU), same folded
// 0-conflict frag addressing.  Barriers only at the 6 cig boundaries
// (A-patch restage).  Epilogue: LSTM in-register, c NCHW f32x4 I/O.

#define SMEM_G (25344 + 49152)

__global__ __launch_bounds__(256, 2) void kgates(
    const f16* __restrict__ xp, const f16* __restrict__ hp,
    const f16* __restrict__ wg, const float* __restrict__ bg,
    float* __restrict__ cbuf, f16* __restrict__ hslot) {
  extern __shared__ char smem[];
  f16* Ap = (f16*)smem;                    // [3][132][32]
  const int tid = threadIdx.x;
  const int lane = tid & 63;
  const int w = tid >> 6;                  // wave = N quadrant
  f16* Bw = (f16*)(smem + 25344 + w * 12288);   // private ring [3][64][32]
  const int l15 = lane & 15;
  const int q = lane >> 4;
  const int y = blockIdx.x;
  const int b = blockIdx.y;
  const int z = blockIdx.z;
  const int n0 = z * 256;
  const int chunk = (lane & 3) ^ ((lane >> 3) & 3);
  const int bq8 = (q ^ ((l15 >> 1) & 3)) << 3;   // B swizzle: per-thread const

  f32x4 acc[8][4] = {};

  // per-thread B source base: global row = n0 + w*64 + (lane>>2) (+ii*16)
  const f16* wgthr = wg + (size_t)(n0 + w * 64 + (lane >> 2)) * 192 + chunk * 8;

  auto stageA = [&](int cig) {
    const f16* S; int CS, cigl;
    if (cig < 2) { S = xp; CS = 64;  cigl = cig; }
    else         { S = hp; CS = 128; cigl = cig - 2; }
    for (int i = w; i < 27; i += 4) {
      int dy = i / 9, sub = i - dy * 9;
      int xp0 = sub * 16;
      const f16* src = S +
          ((size_t)((b * 130 + y + dy) * 130 + xp0 + (lane >> 2))) * CS +
          cigl * 32 + chunk * 8;
      f16* dst = Ap + (dy * 132 + xp0) * 32;
      if (sub == 8) { if (lane < 16) gld_lds16(dst, src); }
      else gld_lds16(dst, src);
    }
  };
  auto stageB = [&](int j) {               // 4 loads, own 64 rows (16/load)
    int cig = j / 9, tap = j - cig * 9;
    f16* dst = Bw + (j % 3) * 2048;
    const f16* src = wgthr + (size_t)tap * (512 * 192) + cig * 32;
#pragma unroll
    for (int ii = 0; ii < 4; ++ii)
      gld_lds16(dst + ii * 512, src + ii * 3072);
  };

  // prologue: A(0) [<=7 loads] + own B(0) + B(1); wait A+B0 done
  stageA(0);
  stageB(0);
  stageB(1);
  asm volatile("s_waitcnt vmcnt(4)" ::: "memory");
  __builtin_amdgcn_s_barrier();

  for (int j = 0; j < 54; ++j) {
    const int cig = j / 9, tap = j - cig * 9;
    const int dy = tap / 3, dx = tap - dy * 3;

    if (j + 2 < 54) {
      stageB(j + 2);                       // own slot (j+2)%3, read at j-1: free
      asm volatile("s_waitcnt vmcnt(8)" ::: "memory");   // B(j) landed
    } else if (j == 52) {
      asm volatile("s_waitcnt vmcnt(4)" ::: "memory");
    } else {
      asm volatile("s_waitcnt vmcnt(0)" ::: "memory");
    }

    const int rr = l15 + dx;
    const f16* abase = Ap + dy * (132 * 32) + rr * 32 +
                       ((q ^ ((rr >> 1) & 3)) << 3);
    const f16* bbase = Bw + (j % 3) * 2048 + l15 * 32 + bq8;
    f16x8 af[8], bfr[4];
#pragma unroll
    for (int mf = 0; mf < 8; ++mf) af[mf] = *(const f16x8*)(abase + mf * 512);
#pragma unroll
    for (int nf = 0; nf < 4; ++nf) bfr[nf] = *(const f16x8*)(bbase + nf * 512);

    __builtin_amdgcn_s_setprio(1);
#pragma unroll
    for (int mf = 0; mf < 8; ++mf)
#pragma unroll
      for (int nf = 0; nf < 4; ++nf)
        acc[mf][nf] = __builtin_amdgcn_mfma_f32_16x16x32_f16(af[mf], bfr[nf], acc[mf][nf], 0, 0, 0);
    __builtin_amdgcn_s_setprio(0);

    if (tap == 8) {                        // cig boundary: only sync point
      __builtin_amdgcn_s_barrier();        // all waves done reading Ap
      if (cig < 5) stageA(cig + 1);
      asm volatile("s_waitcnt vmcnt(0)" ::: "memory");
      __builtin_amdgcn_s_barrier();
    }
  }

  // fused LSTM epilogue: acc[mf][gate][r]; c in NCHW -> f32x4 I/O
  const int hch = z * 64 + w * 16 + l15;
  const float bi  = bg[hch];
  const float bf2 = bg[128 + hch];
  const float bo2 = bg[256 + hch];
  const float bg2 = bg[384 + hch];
  float* crow = cbuf + ((size_t)(b * 128 + hch) * 128 + y) * 128;
  f16* hrow = hslot + ((size_t)((b * 130 + y + 1) * 130 + 1)) * 128 + hch;
#pragma unroll
  for (int mf = 0; mf < 8; ++mf) {
    const int px0 = mf * 16 + q * 4;
    f32x4 co = *(const f32x4*)(crow + px0);
    f32x4 cn;
    f16 hv[4];
#pragma unroll
    for (int r = 0; r < 4; ++r) {
      float iv = sigf(acc[mf][0][r] + bi);
      float fv = sigf(acc[mf][1][r] + bf2);
      float ov = sigf(acc[mf][2][r] + bo2);
      float gv = tanh_fast(acc[mf][3][r] + bg2);
      float cv = fv * co[r] + iv * gv;
      cn[r] = cv;
      hv[r] = (f16)(ov * tanh_fast(cv));
    }
    *(f32x4*)(crow + px0) = cn;
#pragma unroll
    for (int r = 0; r < 4; ++r) hrow[(size_t)(px0 + r) * 128] = hv[r];
  }
}

// ---------------- output conv, batched over 4 timesteps: M=131072 N=64 K=1152 ----
// block: 128 px row x 64 couts; 4 waves M-split, wave tile 32x64 (acc[2][4]).
// R11 form: counted-vmcnt ring-3 pipeline, issue-early; folded frag addrs.

#define SMEM_O (25344 + 12288)

__global__ __launch_bounds__(256, 4) void koutconv(
    const f16* __restrict__ hr, int slot0, const f16* __restrict__ wo,
    const float* __restrict__ bo, float* __restrict__ outb) {
  extern __shared__ char smem[];
  f16* Ap = (f16*)smem;                    // [3][132][32]
  f16* Br = (f16*)(smem + 25344);          // ring [3][64][32]
  const int tid = threadIdx.x, lane = tid & 63, w = tid >> 6;
  const int l15 = lane & 15, q = lane >> 4;
  const int y = blockIdx.x;
  const int b = blockIdx.y;
  const int ts = blockIdx.z;
  const f16* hp = hr + (size_t)((slot0 + ts) % 5) * SLICE_H;
  float* outt = outb + (size_t)ts * 2 * 64 * 16384;
  const int chunk = (lane & 3) ^ ((lane >> 3) & 3);
  const int bq8 = (q ^ ((l15 >> 1) & 3)) << 3;

  f32x4 acc[2][4] = {};

  const f16* wothr = wo + (size_t)(w * 16 + (lane >> 2)) * 128 + chunk * 8;

  auto stageA = [&](int cig) {
    for (int i = w; i < 27; i += 4) {
      int dy = i / 9, sub = i - dy * 9;
      int xp0 = sub * 16;
      const f16* src = hp +
          ((size_t)((b * 130 + y + dy) * 130 + xp0 + (lane >> 2))) * 128 +
          cig * 32 + chunk * 8;
      f16* dst = Ap + (dy * 132 + xp0) * 32;
      if (sub == 8) { if (lane < 16) gld_lds16(dst, src); }
      else gld_lds16(dst, src);
    }
  };
  auto stageB = [&](int j) {               // 1 load/wave
    int cig = j / 9, tap = j - cig * 9;
    gld_lds16(Br + (j % 3) * 2048 + w * 512,
              wothr + (size_t)tap * (64 * 128) + cig * 32);
  };

  stageA(0);
  stageB(0);
  stageB(1);
  asm volatile("s_waitcnt vmcnt(1)" ::: "memory");
  __builtin_amdgcn_s_barrier();

  for (int cig = 0; cig < 4; ++cig) {
    for (int tap = 0; tap < 9; ++tap) {
      const int j = cig * 9 + tap;
      const int dy = tap / 3, dx = tap - dy * 3;

      if (j + 2 < 36) stageB(j + 2);

      const f16* Bc = Br + (j % 3) * 2048;
      const int rr = l15 + dx;
      const f16* abase = Ap + dy * (132 * 32) + (w * 32 + rr) * 32 +
                         ((q ^ ((rr >> 1) & 3)) << 3);
      const f16* bbase = Bc + l15 * 32 + bq8;
      f16x8 af[2], bfr[4];
#pragma unroll
      for (int mf = 0; mf < 2; ++mf) af[mf] = *(const f16x8*)(abase + mf * 512);
#pragma unroll
      for (int nf = 0; nf < 4; ++nf) bfr[nf] = *(const f16x8*)(bbase + nf * 512);

      __builtin_amdgcn_s_setprio(1);
#pragma unroll
      for (int mf = 0; mf < 2; ++mf)
#pragma unroll
        for (int nf = 0; nf < 4; ++nf)
          acc[mf][nf] = __builtin_amdgcn_mfma_f32_16x16x32_f16(af[mf], bfr[nf], acc[mf][nf], 0, 0, 0);
      __builtin_amdgcn_s_setprio(0);

      if (tap == 8) {
        __builtin_amdgcn_s_barrier();
        if (cig < 3) stageA(cig + 1);
        asm volatile("s_waitcnt vmcnt(0)" ::: "memory");
        __builtin_amdgcn_s_barrier();
      } else {
        if (j + 2 < 36) asm volatile("s_waitcnt vmcnt(1)" ::: "memory");
        else            asm volatile("s_waitcnt vmcnt(0)" ::: "memory");
        __builtin_amdgcn_s_barrier();
      }
    }
  }

#pragma unroll
  for (int nf = 0; nf < 4; ++nf) {
    int cout = nf * 16 + l15;
    float bias = bo[cout];
#pragma unroll
    for (int mf = 0; mf < 2; ++mf) {
      int xbase = w * 32 + mf * 16 + q * 4;
      f32x4 v = acc[mf][nf];
      v[0] += bias; v[1] += bias; v[2] += bias; v[3] += bias;
      *(f32x4*)(outt + (((size_t)b * 64 + cout) * 128 + y) * 128 + xbase) = v;
    }
  }
}

// ---------------- host ----------------

extern "C" void kernel_launch(void* const* d_in, const int* in_sizes, int n_in,
                              void* d_out, int out_size, void* d_ws, size_t ws_size,
                              hipStream_t stream) {
  const float* x  = (const float*)d_in[0];
  const float* Wg = (const float*)d_in[1];
  const float* bg = (const float*)d_in[2];
  const float* Wo = (const float*)d_in[3];
  const float* bo = (const float*)d_in[4];
  float* out = (float*)d_out;

  char* base = (char*)d_ws;
  size_t off = 0;
  auto carve = [&](size_t bytes) {
    char* p = base + off;
    off += (bytes + 1023) & ~(size_t)1023;
    return p;
  };
  const size_t PADPOS = (size_t)2 * 130 * 130;           // 33800 padded positions
  const size_t xpad_b  = PADPOS * 64 * 2 + 1024;          // f16
  const size_t hring_b = (size_t)5 * SLICE_H * 2 + 1024;  // 5 padded h slices, f16
  const size_t c_b = (size_t)2 * 128 * 128 * 128 * 4;     // fp32 cell state (NCHW)

  f16* xp    = (f16*)carve(xpad_b);
  f16* hr    = (f16*)carve(hring_b);
  float* cbuf = (float*)carve(c_b);
  f16* wg    = (f16*)carve((size_t)9 * 512 * 192 * 2);
  f16* wo    = (f16*)carve((size_t)9 * 64 * 128 * 2);

  // zero state + pad borders once (in-stream: graph-replay deterministic;
  // interiors are fully rewritten every use, borders stay zero)
  hipMemsetAsync(xp, 0, xpad_b, stream);
  hipMemsetAsync(hr, 0, hring_b, stream);
  hipMemsetAsync(cbuf, 0, c_b, stream);

  kwtg<<<(9 * 512 * 192 + 255) / 256, 256, 0, stream>>>(Wg, wg);
  kwt<<<(9 * 64 * 128 + 255) / 256, 256, 0, stream>>>(Wo, wo, 64 * 128);

  for (int t = 0; t < 12; ++t) {
    const float* xt = x + (size_t)t * 2 * 64 * 16384;
    kxform<<<128, 256, 0, stream>>>(xt, xp);
    kgates<<<dim3(128, 2, 2), 256, SMEM_G, stream>>>(
        xp, hr + (size_t)(t % 5) * SLICE_H, wg, bg, cbuf,
        hr + (size_t)((t + 1) % 5) * SLICE_H);
    if ((t & 3) == 3) {
      koutconv<<<dim3(128, 2, 4), 256, SMEM_O, stream>>>(
          hr, (t - 2) % 5, wo, bo, out + (size_t)(t - 3) * 2 * 64 * 16384);
    }
  }
}